// Round 15
// baseline (273.530 us; speedup 1.0000x reference)
//
#include <hip/hip_runtime.h>
#include <hip/hip_bf16.h>
#include <math.h>

#define LYR 8
#define SEQ 4096
#define DIM 2048
#define NH 16
#define HD 128
#define NQ 32
#define NKV 256   // KVH*HD
#define NQE 2048  // H*HD

typedef __attribute__((ext_vector_type(8))) short short8;
typedef __attribute__((ext_vector_type(4))) float f32x4;

// workspace layout (float units)
#define WS_ABLOB 256                       // 524288
#define WS_COS   524544                    // 524288
#define WS_SIN   1048832                   // 524288
#define WS_QBUF  1573120                   // 524288
#define WS_PART  2097408                   // 4194304 (16MB, ks=8 partials)
#define WS_W2    6291712                   // 4194304 floats = 8388608 shorts
#define WS_KBLOB 10486016                  // 8388608 floats = 16777216 shorts
// end 18874624 floats ~ 75.5 MB

__device__ __forceinline__ short f2bf(float x) {
  __hip_bfloat16 h = __float2bfloat16(x);
  return *(short*)&h;
}
__device__ __forceinline__ float bf2f(short s) {
  unsigned u = ((unsigned)(unsigned short)s) << 16;
  return __uint_as_float(u);
}

// cheap exact split: hi = truncate-to-bf16 (exact residual), lo = rne bf16 of residual
__device__ __forceinline__ void split1(float x, short& h, short& l) {
  unsigned b = __float_as_uint(x);
  h = (short)(b >> 16);
  float lo = x - __uint_as_float(b & 0xffff0000u);
  l = (short)((__float_as_uint(lo) + 0x8000u) >> 16);
}

#define GLOAD16(srcp, dstp) \
  __builtin_amdgcn_global_load_lds( \
      (const __attribute__((address_space(1))) unsigned int*)(srcp), \
      (__attribute__((address_space(3))) unsigned int*)(dstp), 16, 0, 0)

// raw barrier: drain LDS ops only; leave global loads in flight across the barrier
#define RBAR() asm volatile("s_waitcnt lgkmcnt(0)\n\ts_barrier" ::: "memory")

// ---------------- prep: W' = ln_w*k_w -> frag-lane-linear bf16 hi/lo blob ----------------
__global__ __launch_bounds__(256) void prep_kernel(
    const float* __restrict__ ln_w, const float* __restrict__ k_w,
    short* __restrict__ W2) {
  int kb = blockIdx.x, l = blockIdx.y, t = threadIdx.x;
  const float* kwl = k_w + (size_t)l * DIM * NKV;
  const float* lnl = ln_w + l * DIM;
  short* blob = W2 + (size_t)(l * 64 + kb) * 16384;
  #pragma unroll
  for (int i = 0; i < 4; ++i) {
    int p = t + i * 256;
    int fi = p >> 6, lane = p & 63;
    int n = fi * 16 + (lane & 15);
    int k0 = kb * 32 + (lane >> 4) * 8;
    short hi8[8], lo8[8];
    #pragma unroll
    for (int e = 0; e < 8; ++e) {
      float v = lnl[k0 + e] * kwl[(size_t)(k0 + e) * NKV + n];
      short h = f2bf(v);
      hi8[e] = h;
      lo8[e] = f2bf(v - bf2f(h));
    }
    *(short8*)(blob + p * 8) = *(short8*)hi8;
    *(short8*)(blob + 8192 + p * 8) = *(short8*)lo8;
  }
}

// ---------------- cossin: mrope tables [S][HD] ----------------
__global__ void cossin_kernel(const int* __restrict__ pos_ids,
                              float* __restrict__ cost, float* __restrict__ sint) {
  int idx = blockIdx.x * 256 + threadIdx.x;
  int s = idx >> 7, d = idx & 127;
  int t = (d < 32) ? 0 : (d < 80 ? 1 : 2);
  int j = d & 63;
  double invf = pow(1000000.0, -(double)j / 64.0);
  double ph = (double)pos_ids[t * SEQ + s] * invf;
  cost[idx] = (float)cos(ph);
  sint[idx] = (float)sin(ph);
}

// ---------------- xqt2: fused inv_rms + A-frag blob for Q proj ----------------
__global__ __launch_bounds__(256) void xqt_kernel(
    const float* __restrict__ hs, const float* __restrict__ ln_w,
    const int* __restrict__ q_idx, short* __restrict__ Ablob) {
  __shared__ int qix[32];
  __shared__ float qir[32];
  int l = blockIdx.x, t = threadIdx.x;
  if (t < 32) qix[t] = q_idx[t];
  __syncthreads();
  // phase 1: sumsq per row (8 threads/row, 256 floats each)
  {
    int row = t >> 3, seg = t & 7;
    const float* src = hs + ((size_t)l * SEQ + qix[row]) * DIM + seg * 256;
    float sq = 0.f;
    #pragma unroll
    for (int i = 0; i < 64; ++i) {
      float4 v = *(const float4*)(src + i * 4);
      sq = fmaf(v.x, v.x, fmaf(v.y, v.y, fmaf(v.z, v.z, fmaf(v.w, v.w, sq))));
    }
    sq += __shfl_xor(sq, 1);
    sq += __shfl_xor(sq, 2);
    sq += __shfl_xor(sq, 4);
    if (seg == 0) qir[row] = rsqrtf(sq / (float)DIM + 1e-6f);
  }
  __syncthreads();
  int lane = t & 63, g4 = t >> 6;
  short* base = Ablob + (size_t)l * 131072;
  int row = lane & 15, kgl = lane >> 4;
  for (int i = 0; i < 64; ++i) {
    int group = g4 * 64 + i;                 // (kb, half, mf)
    int kb = group >> 2, half = (group >> 1) & 1, mf = group & 1;
    int r = row + mf * 16;
    int k0 = kb * 32 + kgl * 8;
    const float* src = hs + ((size_t)l * SEQ + qix[r]) * DIM + k0;
    const float* lnp = ln_w + l * DIM + k0;
    float ir = qir[r];
    float4 v0 = *(const float4*)src;
    float4 v1 = *(const float4*)(src + 4);
    float4 w0 = *(const float4*)lnp;
    float4 w1 = *(const float4*)(lnp + 4);
    float av[8] = {v0.x*w0.x, v0.y*w0.y, v0.z*w0.z, v0.w*w0.w,
                   v1.x*w1.x, v1.y*w1.y, v1.z*w1.z, v1.w*w1.w};
    short o8[8];
    #pragma unroll
    for (int e = 0; e < 8; ++e) {
      float v = av[e] * ir;
      short hh, ll;
      split1(v, hh, ll);
      o8[e] = half ? ll : hh;
    }
    *(short8*)(base + group * 512 + lane * 8) = *(short8*)o8;
  }
}

// ---------------- kgemm: K proj bf16x3 MFMA, 2-phase-per-step CONVOY schedule ----------------
__global__ __launch_bounds__(256) void kgemm_kernel(
    const float* __restrict__ hs, const short* __restrict__ W2,
    const float* __restrict__ k_b, const float* __restrict__ cost,
    const float* __restrict__ sint, short* __restrict__ Kblob) {
  __shared__ __align__(1024) char SM[65536];

  int t = threadIdx.x;
  int fid = blockIdx.x;
  int l = fid & 7, sb = fid >> 3;
  int s0 = sb * 64;
  int lane = t & 63, w = t >> 6;
  int fr = lane & 15, kg = lane >> 4;
  int arow = t >> 2, akg = t & 3;

  const float* hrow = hs + ((size_t)l * SEQ + s0 + arow) * DIM + akg * 8;
  const char* wbase = (const char*)(W2 + (size_t)l * 64 * 16384);
  const char* wfrag = wbase + w * 1024 + lane * 16;

  int awoff = (arow >> 4) * 1024 + (((akg * 16 + (arow & 15)) * 16) ^ (akg << 5));
  int aroff = (lane * 16) ^ ((lane >> 4) << 5);

  f32x4 acc[4][4];
  #pragma unroll
  for (int mf = 0; mf < 4; ++mf)
    #pragma unroll
    for (int nf = 0; nf < 4; ++nf) acc[mf][nf] = (f32x4){0.f, 0.f, 0.f, 0.f};
  float sq = 0.f;
  float4 rA0, rA1, rB0, rB1;
  short8 B0h[4], B0l[4], B1h[4], B1l[4];

  {
    #pragma unroll
    for (int nf = 0; nf < 4; ++nf) {
      B0h[nf] = *(const short8*)(wfrag + nf * 4096);
      B0l[nf] = *(const short8*)(wfrag + nf * 4096 + 16384);
    }
    float4 a0 = *(const float4*)(hrow);
    float4 a1 = *(const float4*)(hrow + 4);
    float av[8] = {a0.x, a0.y, a0.z, a0.w, a1.x, a1.y, a1.z, a1.w};
    short hi8[8], lo8[8];
    #pragma unroll
    for (int e = 0; e < 8; ++e) {
      sq = fmaf(av[e], av[e], sq);
      split1(av[e], hi8[e], lo8[e]);
    }
    *(short8*)(SM + awoff) = *(short8*)hi8;
    *(short8*)(SM + 4096 + awoff) = *(short8*)lo8;
    rA0 = *(const float4*)(hrow + 32);
    rA1 = *(const float4*)(hrow + 36);
  }
  RBAR();

#define KSTEP8(KB, CA0, CA1, NA0, NA1, UBH, UBL, PBH, PBL) do { \
    int buf_ = (KB) & 1; \
    const char* asb_ = SM + buf_ * 8192; \
    if ((KB) < 63) { \
      const char* bsrc_ = wfrag + (size_t)((KB) + 1) * 32768; \
      _Pragma("unroll") \
      for (int nf = 0; nf < 4; ++nf) { \
        PBH[nf] = *(const short8*)(bsrc_ + nf * 4096); \
        PBL[nf] = *(const short8*)(bsrc_ + nf * 4096 + 16384); \
      } \
    } \
    if ((KB) < 62) { \
      NA0 = *(const float4*)(hrow + ((KB) + 2) * 32); \
      NA1 = *(const float4*)(hrow + ((KB) + 2) * 32 + 4); \
    } \
    short8 ah_[4], al_[4]; \
    _Pragma("unroll") \
    for (int mf = 0; mf < 4; ++mf) { \
      ah_[mf] = *(const short8*)(asb_ + mf * 1024 + aroff); \
      al_[mf] = *(const short8*)(asb_ + 4096 + mf * 1024 + aroff); \
    } \
    __builtin_amdgcn_s_barrier(); \
    asm volatile("s_waitcnt lgkmcnt(0)" ::: "memory"); \
    __builtin_amdgcn_s_setprio(1); \
    _Pragma("unroll") \
    for (int nf = 0; nf < 2; ++nf) \
      _Pragma("unroll") \
      for (int mf = 0; mf < 4; ++mf) \
        acc[mf][nf] = __builtin_amdgcn_mfma_f32_16x16x32_bf16(ah_[mf], UBH[nf], acc[mf][nf], 0, 0, 0); \
    _Pragma("unroll") \
    for (int nf = 0; nf < 2; ++nf) \
      _Pragma("unroll") \
      for (int mf = 0; mf < 4; ++mf) \
        acc[mf][nf] = __builtin_amdgcn_mfma_f32_16x16x32_bf16(ah_[mf], UBL[nf], acc[mf][nf], 0, 0, 0); \
    _Pragma("unroll") \
    for (int nf = 0; nf < 2; ++nf) \
      _Pragma("unroll") \
      for (int mf = 0; mf < 4; ++mf) \
        acc[mf][nf] = __builtin_amdgcn_mfma_f32_16x16x32_bf16(al_[mf], UBH[nf], acc[mf][nf], 0, 0, 0); \
    __builtin_amdgcn_s_setprio(0); \
    __builtin_amdgcn_s_barrier(); \
    if ((KB) < 63) { \
      char* asn_ = SM + (buf_ ^ 1) * 8192; \
      float av_[8] = {CA0.x, CA0.y, CA0.z, CA0.w, CA1.x, CA1.y, CA1.z, CA1.w}; \
      short hi8_[8], lo8_[8]; \
      _Pragma("unroll") \
      for (int e = 0; e < 8; ++e) { \
        sq = fmaf(av_[e], av_[e], sq); \
        split1(av_[e], hi8_[e], lo8_[e]); \
      } \
      *(short8*)(asn_ + awoff) = *(short8*)hi8_; \
      *(short8*)(asn_ + 4096 + awoff) = *(short8*)lo8_; \
    } \
    __builtin_amdgcn_s_setprio(1); \
    _Pragma("unroll") \
    for (int nf = 2; nf < 4; ++nf) \
      _Pragma("unroll") \
      for (int mf = 0; mf < 4; ++mf) \
        acc[mf][nf] = __builtin_amdgcn_mfma_f32_16x16x32_bf16(ah_[mf], UBH[nf], acc[mf][nf], 0, 0, 0); \
    _Pragma("unroll") \
    for (int nf = 2; nf < 4; ++nf) \
      _Pragma("unroll") \
      for (int mf = 0; mf < 4; ++mf) \
        acc[mf][nf] = __builtin_amdgcn_mfma_f32_16x16x32_bf16(ah_[mf], UBL[nf], acc[mf][nf], 0, 0, 0); \
    _Pragma("unroll") \
    for (int nf = 2; nf < 4; ++nf) \
      _Pragma("unroll") \
      for (int mf = 0; mf < 4; ++mf) \
        acc[mf][nf] = __builtin_amdgcn_mfma_f32_16x16x32_bf16(al_[mf], UBH[nf], acc[mf][nf], 0, 0, 0); \
    __builtin_amdgcn_s_setprio(0); \
    asm volatile("s_waitcnt lgkmcnt(0)" ::: "memory"); \
    __builtin_amdgcn_s_barrier(); \
  } while (0)

  for (int kb2 = 0; kb2 < 32; ++kb2) {
    KSTEP8(2 * kb2,     rA0, rA1, rB0, rB1, B0h, B0l, B1h, B1l);
    KSTEP8(2 * kb2 + 1, rB0, rB1, rA0, rA1, B1h, B1l, B0h, B0l);
  }
#undef KSTEP8

  // ---- epilogue ----
  sq += __shfl_xor(sq, 1);
  sq += __shfl_xor(sq, 2);
  float* smf = (float*)SM;
  __syncthreads();
  if ((t & 3) == 0) smf[arow] = sq;
  __syncthreads();
  float irv[16];
  #pragma unroll
  for (int mf = 0; mf < 4; ++mf)
    #pragma unroll
    for (int r = 0; r < 4; ++r)
      irv[mf * 4 + r] = rsqrtf(smf[mf * 16 + kg * 4 + r] / (float)DIM + 1e-6f);
  __syncthreads();

  float* Kraw = smf;   // [64][256] with column XOR swizzle (row&7)<<2
  int j = w * 16 + fr;
  float bias0 = k_b[l * NKV + j];
  float bias1 = k_b[l * NKV + j + 64];
  float bias2 = k_b[l * NKV + j + 128];
  float bias3 = k_b[l * NKV + j + 192];
  #pragma unroll
  for (int mf = 0; mf < 4; ++mf) {
    #pragma unroll
    for (int r = 0; r < 4; ++r) {
      int row = mf * 16 + kg * 4 + r;
      int s = s0 + row;
      float ir = irv[mf * 4 + r];
      float v0 = acc[mf][0][r] * ir + bias0;
      float v1 = acc[mf][1][r] * ir + bias1;
      float v2 = acc[mf][2][r] * ir + bias2;
      float v3 = acc[mf][3][r] * ir + bias3;
      float cj = cost[s * HD + j], sj = sint[s * HD + j];
      float cj2 = cost[s * HD + j + 64], sj2 = sint[s * HD + j + 64];
      int sw = (row & 7) << 2;
      float* kr = Kraw + row * 256;
      kr[j ^ sw]           = v0 * cj - v1 * sj;
      kr[(j + 64) ^ sw]    = v1 * cj2 + v0 * sj2;
      kr[(j + 128) ^ sw]   = v2 * cj - v3 * sj;
      kr[(j + 192) ^ sw]   = v3 * cj2 + v2 * sj2;
    }
  }
  __syncthreads();

  int kc = sb >> 1, fb = (sb & 1) * 4;
  #pragma unroll
  for (int i = 0; i < 8; ++i) {
    int c = t + i * 256;
    int lc = c & 63, fl = (c >> 6) & 3, ts2 = (c >> 8) & 3, kv = c >> 10;
    int key = fl * 16 + (lc & 15);
    int d0 = kv * 128 + ts2 * 32 + (lc >> 4) * 8;
    int sw = (key & 7) << 2;
    float4 x0 = *(const float4*)(Kraw + key * 256 + (d0 ^ sw));
    float4 x1 = *(const float4*)(Kraw + key * 256 + ((d0 + 4) ^ sw));
    float av[8] = {x0.x, x0.y, x0.z, x0.w, x1.x, x1.y, x1.z, x1.w};
    short hi8[8], lo8[8];
    #pragma unroll
    for (int e = 0; e < 8; ++e) split1(av[e], hi8[e], lo8[e]);
    short* bb = Kblob + (size_t)((l * 2 + kv) * 32 + kc) * 32768
              + (size_t)((ts2 * 2 + 0) * 8 + fb + fl) * 512 + lc * 8;
    *(short8*)bb = *(short8*)hi8;
    *(short8*)(bb + 4096) = *(short8*)lo8;
  }
}

// ---------------- qgemm: Q = xq . q_w via bf16x3 MFMA; ks=8, nc=128, 2 blocks/CU ----------------
__global__ __launch_bounds__(256) void qgemm_kernel(
    const float* __restrict__ q_w, const short* __restrict__ Ablob,
    float* __restrict__ part) {
  __shared__ __align__(1024) char SM[65536];  // A 32KB | B dbuf 2x16KB
  int t = threadIdx.x;
  int nc = blockIdx.x, ks = blockIdx.y, l = blockIdx.z;
  int lane = t & 63, w = t >> 6;
  int fr = lane & 15, kg = lane >> 4;
  const char* abase = (const char*)(Ablob + (size_t)l * 131072 + (size_t)ks * 16384);
  const float* qwl = q_w + (size_t)l * DIM * NQE;

  #pragma unroll
  for (int c = 0; c < 8; ++c) {
    int chunk = w * 8 + c;
    GLOAD16(abase + chunk * 1024 + lane * 16, SM + chunk * 1024);
  }
  #pragma unroll
  for (int c = 0; c < 4; ++c) {
    int r2 = (w * 4 + c) * 2;
    const char* src = (const char*)(qwl + (size_t)(ks * 256 + r2 + (lane >> 5)) * NQE + nc * 128) + (lane & 31) * 16;
    GLOAD16(src, SM + 32768 + (w * 4 + c) * 1024);
  }
  f32x4 acc[2][2];
  #pragma unroll
  for (int mf = 0; mf < 2; ++mf)
    #pragma unroll
    for (int nf = 0; nf < 2; ++nf) acc[mf][nf] = (f32x4){0.f, 0.f, 0.f, 0.f};
  __syncthreads();

  for (int ts = 0; ts < 8; ++ts) {
    int buf = ts & 1;
    if (ts < 7) {
      #pragma unroll
      for (int c = 0; c < 4; ++c) {
        int r2 = (w * 4 + c) * 2;
        const char* src = (const char*)(qwl + (size_t)(ks * 256 + (ts + 1) * 32 + r2 + (lane >> 5)) * NQE + nc * 128) + (lane & 31) * 16;
        GLOAD16(src, SM + 32768 + (buf ^ 1) * 16384 + (w * 4 + c) * 1024);
      }
    }
    short8 ah[2], al[2];
    #pragma unroll
    for (int mf = 0; mf < 2; ++mf) {
      ah[mf] = *(const short8*)(SM + ts * 4096 + mf * 1024 + lane * 16);
      al[mf] = *(const short8*)(SM + ts * 4096 + 2048 + mf * 1024 + lane * 16);
    }
    const float* bt = (const float*)(SM + 32768 + buf * 16384);
    short8 bh[2], bl[2];
    #pragma unroll
    for (int nf = 0; nf < 2; ++nf) {
      int c = w * 32 + nf * 16 + fr;
      short bh8[8], bl8[8];
      #pragma unroll
      for (int e = 0; e < 8; ++e) {
        float v = bt[(kg * 8 + e) * 128 + c];
        split1(v, bh8[e], bl8[e]);
      }
      bh[nf] = *(short8*)bh8;
      bl[nf] = *(short8*)bl8;
    }
    #pragma unroll
    for (int nf = 0; nf < 2; ++nf)
      #pragma unroll
      for (int mf = 0; mf < 2; ++mf)
        acc[mf][nf] = __builtin_amdgcn_mfma_f32_16x16x32_bf16(ah[mf], bh[nf], acc[mf][nf], 0, 0, 0);
    #pragma unroll
    for (int nf = 0; nf < 2; ++nf)
      #pragma unroll
      for (int mf = 0; mf < 2; ++mf)
        acc[mf][nf] = __builtin_amdgcn_mfma_f32_16x16x32_bf16(ah[mf], bl[nf], acc[mf][nf], 0, 0, 0);
    #pragma unroll
    for (int nf = 0; nf < 2; ++nf)
      #pragma unroll
      for (int mf = 0; mf < 2; ++mf)
        acc[mf][nf] = __builtin_amdgcn_mfma_f32_16x16x32_bf16(al[mf], bh[nf], acc[mf][nf], 0, 0, 0);
    __syncthreads();
  }

  #pragma unroll
  for (int mf = 0; mf < 2; ++mf) {
    #pragma unroll
    for (int r = 0; r < 4; ++r) {
      int row = mf * 16 + kg * 4 + r;
      float* prow = part + ((size_t)((ks * LYR + l) * NQ + row)) * NQE + nc * 128;
      #pragma unroll
      for (int nf = 0; nf < 2; ++nf) {
        int col = w * 32 + nf * 16 + fr;
        prow[col] = acc[mf][nf][r];
      }
    }
  }
}

// ---------------- qred: sum 8 k-split partials + bias -> Qbuf ----------------
__global__ __launch_bounds__(256) void qred_kernel(
    const float* __restrict__ part, const float* __restrict__ q_b,
    float* __restrict__ Qbuf) {
  int idx = blockIdx.x * 256 + threadIdx.x;
  int n = idx & 2047, q = (idx >> 11) & 31, l = idx >> 16;
  float v = q_b[l * NQE + n];
  #pragma unroll
  for (int ks = 0; ks < 8; ++ks)
    v += part[((size_t)((ks * LYR + l) * NQ + q)) * NQE + n];
  Qbuf[((size_t)l * NQ + q) * NQE + n] = v;
}

// ---------------- attn: fused rope + scores + mask + softmax ----------------
// block = (l, h, 8 q-rows); S row in LDS fp32; K streamed global->reg from Kblob;
// XCD-bijective decode keeps each XCD's K-set L2-resident. Rope applied in-register
// during A-fragment build (reads Qbuf + cos/sin directly).
__global__ __launch_bounds__(512) void attn_kernel(
    const float* __restrict__ Qbuf, const float* __restrict__ cost,
    const float* __restrict__ sint, const short* __restrict__ Kblob,
    const int* __restrict__ q_idx, float* __restrict__ out) {
  __shared__ float smS[8 * 4104];   // 131328 B, row stride 4104 (bank-skewed)
  __shared__ int qiv8[8];
  int t = threadIdx.x;
  int bid = blockIdx.x;
  int xcd = bid & 7, idx = bid >> 3;
  int pp = 2 * xcd + (idx >> 5);
  int l = pp >> 1, kv = pp & 1;
  int hh = (idx >> 2) & 7, qg = idx & 3;
  int h = kv * 8 + hh;
  int q0 = qg * 8;
  int lane = t & 63, w = t >> 6;
  int g = lane >> 4;

  if (t < 8) qiv8[t] = q_idx[q0 + t];

  // A fragments: rope+scale Qbuf rows in-register (rows 0..7 real, 8..15 zero)
  short8 Ah[4], Al[4];
  {
    int arow = lane & 15, akg = lane >> 4;
    if (arow < 8) {
      int s = q_idx[q0 + arow];
      const float* qr = Qbuf + ((size_t)l * NQ + q0 + arow) * NQE + h * HD;
      const float* ct = cost + s * HD;
      const float* st = sint + s * HD;
      const float SC = 0.088388347648318447f;  // 1/sqrt(128)
      #pragma unroll
      for (int ts = 0; ts < 4; ++ts) {
        int d0 = ts * 32 + akg * 8;
        float4 x0 = *(const float4*)(qr + d0);
        float4 x1 = *(const float4*)(qr + d0 + 4);
        float4 p0 = *(const float4*)(qr + (d0 ^ 64));
        float4 p1 = *(const float4*)(qr + (d0 ^ 64) + 4);
        float4 c0 = *(const float4*)(ct + d0);
        float4 c1 = *(const float4*)(ct + d0 + 4);
        float4 s0 = *(const float4*)(st + d0);
        float4 s1 = *(const float4*)(st + d0 + 4);
        float xv[8] = {x0.x, x0.y, x0.z, x0.w, x1.x, x1.y, x1.z, x1.w};
        float pv[8] = {p0.x, p0.y, p0.z, p0.w, p1.x, p1.y, p1.z, p1.w};
        float cv[8] = {c0.x, c0.y, c0.z, c0.w, c1.x, c1.y, c1.z, c1.w};
        float sv[8] = {s0.x, s0.y, s0.z, s0.w, s1.x, s1.y, s1.z, s1.w};
        short hi8[8], lo8[8];
        #pragma unroll
        for (int e = 0; e < 8; ++e) {
          float v = (ts < 2) ? (xv[e] * cv[e] - pv[e] * sv[e])
                             : (xv[e] * cv[e] + pv[e] * sv[e]);
          split1(v * SC, hi8[e], lo8[e]);
        }
        Ah[ts] = *(short8*)hi8;
        Al[ts] = *(short8*)lo8;
      }
    } else {
      short z8[8] = {0, 0, 0, 0, 0, 0, 0, 0};
      #pragma unroll
      for (int ts = 0; ts < 4; ++ts) { Ah[ts] = *(short8*)z8; Al[ts] = *(short8*)z8; }
    }
  }
  const short* kbase = Kblob + (size_t)((l * 2 + kv) * 32) * 32768 + w * 512 + lane * 8;
  short8 K0h[4], K0l[4], K1h[4], K1l[4];
  #pragma unroll
  for (int ts = 0; ts < 4; ++ts) {
    K0h[ts] = *(const short8*)(kbase + ts * 8192);
    K0l[ts] = *(const short8*)(kbase + ts * 8192 + 4096);
  }
  __syncthreads();   // qiv8 visible

#define ACHUNK(KC, CH, CL, NH_, NL_) do { \
    if ((KC) < 31) { \
      const short* nb = kbase + (size_t)((KC) + 1) * 32768; \
      _Pragma("unroll") \
      for (int ts = 0; ts < 4; ++ts) { \
        NH_[ts] = *(const short8*)(nb + ts * 8192); \
        NL_[ts] = *(const short8*)(nb + ts * 8192 + 4096); \
      } \
    } \
    f32x4 acc = (f32x4){0.f, 0.f, 0.f, 0.f}; \
    _Pragma("unroll") \
    for (int ts = 0; ts < 4; ++ts) \
      acc = __builtin_amdgcn_mfma_f32_16x16x32_bf16(Ah[ts], CH[ts], acc, 0, 0, 0); \
    _Pragma("unroll") \
    for (int ts = 0; ts < 4; ++ts) \
      acc = __builtin_amdgcn_mfma_f32_16x16x32_bf16(Ah[ts], CL[ts], acc, 0, 0, 0); \
    _Pragma("unroll") \
    for (int ts = 0; ts < 4; ++ts) \
      acc = __builtin_amdgcn_mfma_f32_16x16x32_bf16(Al[ts], CH[ts], acc, 0, 0, 0); \
    if (g < 2) { \
      int key = (KC) * 128 + w * 16 + (lane & 15); \
      _Pragma("unroll") \
      for (int rr = 0; rr < 4; ++rr) { \
        int r8 = g * 4 + rr; \
        float v = (key > qiv8[r8]) ? -1e9f : acc[rr]; \
        smS[r8 * 4104 + key] = v; \
      } \
    } \
  } while (0)

  for (int kc2 = 0; kc2 < 16; ++kc2) {
    ACHUNK(2 * kc2,     K0h, K0l, K1h, K1l);
    ACHUNK(2 * kc2 + 1, K1h, K1l, K0h, K0l);
  }
#undef ACHUNK

  __syncthreads();
  // softmax: one wave per row
  int srow = w;
  float* S = smS + srow * 4104;
  float mx = -1e30f;
  #pragma unroll
  for (int c = 0; c < 16; ++c) {
    float4 x = *(const float4*)(S + c * 256 + lane * 4);
    mx = fmaxf(mx, fmaxf(fmaxf(x.x, x.y), fmaxf(x.z, x.w)));
  }
  #pragma unroll
  for (int off = 32; off >= 1; off >>= 1) mx = fmaxf(mx, __shfl_xor(mx, off));
  float sum = 0.f;
  #pragma unroll
  for (int c = 0; c < 16; ++c) {
    float4 x = *(const float4*)(S + c * 256 + lane * 4);
    x.x = __expf(x.x - mx); x.y = __expf(x.y - mx);
    x.z = __expf(x.z - mx); x.w = __expf(x.w - mx);
    sum += x.x + x.y + x.z + x.w;
    *(float4*)(S + c * 256 + lane * 4) = x;
  }
  #pragma unroll
  for (int off = 32; off >= 1; off >>= 1) sum += __shfl_xor(sum, off);
  float inv = 1.f / sum;
  float* orow = out + ((size_t)(l * NH + h) * NQ + q0 + srow) * SEQ;
  #pragma unroll
  for (int c = 0; c < 16; ++c) {
    float4 x = *(const float4*)(S + c * 256 + lane * 4);
    x.x *= inv; x.y *= inv; x.z *= inv; x.w *= inv;
    *(float4*)(orow + c * 256 + lane * 4) = x;
  }
}

extern "C" void kernel_launch(void* const* d_in, const int* in_sizes, int n_in,
                              void* d_out, int out_size, void* d_ws, size_t ws_size,
                              hipStream_t stream) {
  const float* hs   = (const float*)d_in[0];
  const float* ln_w = (const float*)d_in[1];
  const float* q_w  = (const float*)d_in[2];
  const float* q_b  = (const float*)d_in[3];
  const float* k_w  = (const float*)d_in[4];
  const float* k_b  = (const float*)d_in[5];
  const int* pos    = (const int*)d_in[6];
  const int* qidx   = (const int*)d_in[7];
  float* out = (float*)d_out;
  float* ws = (float*)d_ws;
  short* Ablob = (short*)(ws + WS_ABLOB);
  float* cost  = ws + WS_COS;
  float* sint  = ws + WS_SIN;
  float* Qbuf  = ws + WS_QBUF;
  float* part  = ws + WS_PART;
  short* W2    = (short*)(ws + WS_W2);
  short* Kblob = (short*)(ws + WS_KBLOB);

  prep_kernel<<<dim3(64, LYR), 256, 0, stream>>>(ln_w, k_w, W2);
  cossin_kernel<<<(SEQ * HD) / 256, 256, 0, stream>>>(pos, cost, sint);
  xqt_kernel<<<LYR, 256, 0, stream>>>(hs, ln_w, qidx, Ablob);
  kgemm_kernel<<<512, 256, 0, stream>>>(hs, W2, k_b, cost, sint, Kblob);
  qgemm_kernel<<<dim3(16, 8, LYR), 256, 0, stream>>>(q_w, Ablob, part);
  qred_kernel<<<2048, 256, 0, stream>>>(part, q_b, Qbuf);
  attn_kernel<<<512, 512, 0, stream>>>(Qbuf, cost, sint, Kblob, qidx, out);
}

// Round 16
// 260.746 us; speedup vs baseline: 1.0490x; 1.0490x over previous
//
#include <hip/hip_runtime.h>
#include <hip/hip_bf16.h>
#include <math.h>

#define LYR 8
#define SEQ 4096
#define DIM 2048
#define NH 16
#define HD 128
#define NQ 32
#define NKV 256   // KVH*HD
#define NQE 2048  // H*HD

typedef __attribute__((ext_vector_type(8))) short short8;
typedef __attribute__((ext_vector_type(4))) float f32x4;

// workspace layout (float units)
#define WS_ABLOB 256                       // 524288
#define WS_COS   524544                    // 524288
#define WS_SIN   1048832                   // 524288
#define WS_PART  2097408                   // 4194304 (16MB, ks=8 partials)
#define WS_W2    6291712                   // 4194304 floats = 8388608 shorts
#define WS_KBLOB 10486016                  // 8388608 floats = 16777216 shorts
#define WS_QROPE 18874624                  // 524288 floats (roped+scaled Q fp32)
// end 19398912 floats ~ 77.6 MB

__device__ __forceinline__ short f2bf(float x) {
  __hip_bfloat16 h = __float2bfloat16(x);
  return *(short*)&h;
}
__device__ __forceinline__ float bf2f(short s) {
  unsigned u = ((unsigned)(unsigned short)s) << 16;
  return __uint_as_float(u);
}

// cheap exact split: hi = truncate-to-bf16 (exact residual), lo = rne bf16 of residual
__device__ __forceinline__ void split1(float x, short& h, short& l) {
  unsigned b = __float_as_uint(x);
  h = (short)(b >> 16);
  float lo = x - __uint_as_float(b & 0xffff0000u);
  l = (short)((__float_as_uint(lo) + 0x8000u) >> 16);
}

#define GLOAD16(srcp, dstp) \
  __builtin_amdgcn_global_load_lds( \
      (const __attribute__((address_space(1))) unsigned int*)(srcp), \
      (__attribute__((address_space(3))) unsigned int*)(dstp), 16, 0, 0)

// raw barrier: drain LDS ops only; leave global loads in flight across the barrier
#define RBAR() asm volatile("s_waitcnt lgkmcnt(0)\n\ts_barrier" ::: "memory")

// ---------------- prep: W' = ln_w*k_w -> frag-lane-linear bf16 hi/lo blob ----------------
__global__ __launch_bounds__(256) void prep_kernel(
    const float* __restrict__ ln_w, const float* __restrict__ k_w,
    short* __restrict__ W2) {
  int kb = blockIdx.x, l = blockIdx.y, t = threadIdx.x;
  const float* kwl = k_w + (size_t)l * DIM * NKV;
  const float* lnl = ln_w + l * DIM;
  short* blob = W2 + (size_t)(l * 64 + kb) * 16384;
  #pragma unroll
  for (int i = 0; i < 4; ++i) {
    int p = t + i * 256;
    int fi = p >> 6, lane = p & 63;
    int n = fi * 16 + (lane & 15);
    int k0 = kb * 32 + (lane >> 4) * 8;
    short hi8[8], lo8[8];
    #pragma unroll
    for (int e = 0; e < 8; ++e) {
      float v = lnl[k0 + e] * kwl[(size_t)(k0 + e) * NKV + n];
      short h = f2bf(v);
      hi8[e] = h;
      lo8[e] = f2bf(v - bf2f(h));
    }
    *(short8*)(blob + p * 8) = *(short8*)hi8;
    *(short8*)(blob + 8192 + p * 8) = *(short8*)lo8;
  }
}

// ---------------- cossin: mrope tables [S][HD] ----------------
__global__ void cossin_kernel(const int* __restrict__ pos_ids,
                              float* __restrict__ cost, float* __restrict__ sint) {
  int idx = blockIdx.x * 256 + threadIdx.x;
  int s = idx >> 7, d = idx & 127;
  int t = (d < 32) ? 0 : (d < 80 ? 1 : 2);
  int j = d & 63;
  double invf = pow(1000000.0, -(double)j / 64.0);
  double ph = (double)pos_ids[t * SEQ + s] * invf;
  cost[idx] = (float)cos(ph);
  sint[idx] = (float)sin(ph);
}

// ---------------- xqt2: fused inv_rms + A-frag blob for Q proj ----------------
__global__ __launch_bounds__(256) void xqt_kernel(
    const float* __restrict__ hs, const float* __restrict__ ln_w,
    const int* __restrict__ q_idx, short* __restrict__ Ablob) {
  __shared__ int qix[32];
  __shared__ float qir[32];
  int l = blockIdx.x, t = threadIdx.x;
  if (t < 32) qix[t] = q_idx[t];
  __syncthreads();
  // phase 1: sumsq per row (8 threads/row, 256 floats each)
  {
    int row = t >> 3, seg = t & 7;
    const float* src = hs + ((size_t)l * SEQ + qix[row]) * DIM + seg * 256;
    float sq = 0.f;
    #pragma unroll
    for (int i = 0; i < 64; ++i) {
      float4 v = *(const float4*)(src + i * 4);
      sq = fmaf(v.x, v.x, fmaf(v.y, v.y, fmaf(v.z, v.z, fmaf(v.w, v.w, sq))));
    }
    sq += __shfl_xor(sq, 1);
    sq += __shfl_xor(sq, 2);
    sq += __shfl_xor(sq, 4);
    if (seg == 0) qir[row] = rsqrtf(sq / (float)DIM + 1e-6f);
  }
  __syncthreads();
  int lane = t & 63, g4 = t >> 6;
  short* base = Ablob + (size_t)l * 131072;
  int row = lane & 15, kgl = lane >> 4;
  for (int i = 0; i < 64; ++i) {
    int group = g4 * 64 + i;                 // (kb, half, mf)
    int kb = group >> 2, half = (group >> 1) & 1, mf = group & 1;
    int r = row + mf * 16;
    int k0 = kb * 32 + kgl * 8;
    const float* src = hs + ((size_t)l * SEQ + qix[r]) * DIM + k0;
    const float* lnp = ln_w + l * DIM + k0;
    float ir = qir[r];
    float4 v0 = *(const float4*)src;
    float4 v1 = *(const float4*)(src + 4);
    float4 w0 = *(const float4*)lnp;
    float4 w1 = *(const float4*)(lnp + 4);
    float av[8] = {v0.x*w0.x, v0.y*w0.y, v0.z*w0.z, v0.w*w0.w,
                   v1.x*w1.x, v1.y*w1.y, v1.z*w1.z, v1.w*w1.w};
    short o8[8];
    #pragma unroll
    for (int e = 0; e < 8; ++e) {
      float v = av[e] * ir;
      short hh, ll;
      split1(v, hh, ll);
      o8[e] = half ? ll : hh;
    }
    *(short8*)(base + group * 512 + lane * 8) = *(short8*)o8;
  }
}

// ---------------- kgemm: K proj bf16x3 MFMA, 2-phase-per-step CONVOY schedule ----------------
__global__ __launch_bounds__(256) void kgemm_kernel(
    const float* __restrict__ hs, const short* __restrict__ W2,
    const float* __restrict__ k_b, const float* __restrict__ cost,
    const float* __restrict__ sint, short* __restrict__ Kblob) {
  __shared__ __align__(1024) char SM[65536];

  int t = threadIdx.x;
  int fid = blockIdx.x;
  int l = fid & 7, sb = fid >> 3;
  int s0 = sb * 64;
  int lane = t & 63, w = t >> 6;
  int fr = lane & 15, kg = lane >> 4;
  int arow = t >> 2, akg = t & 3;

  const float* hrow = hs + ((size_t)l * SEQ + s0 + arow) * DIM + akg * 8;
  const char* wbase = (const char*)(W2 + (size_t)l * 64 * 16384);
  const char* wfrag = wbase + w * 1024 + lane * 16;

  int awoff = (arow >> 4) * 1024 + (((akg * 16 + (arow & 15)) * 16) ^ (akg << 5));
  int aroff = (lane * 16) ^ ((lane >> 4) << 5);

  f32x4 acc[4][4];
  #pragma unroll
  for (int mf = 0; mf < 4; ++mf)
    #pragma unroll
    for (int nf = 0; nf < 4; ++nf) acc[mf][nf] = (f32x4){0.f, 0.f, 0.f, 0.f};
  float sq = 0.f;
  float4 rA0, rA1, rB0, rB1;
  short8 B0h[4], B0l[4], B1h[4], B1l[4];

  {
    #pragma unroll
    for (int nf = 0; nf < 4; ++nf) {
      B0h[nf] = *(const short8*)(wfrag + nf * 4096);
      B0l[nf] = *(const short8*)(wfrag + nf * 4096 + 16384);
    }
    float4 a0 = *(const float4*)(hrow);
    float4 a1 = *(const float4*)(hrow + 4);
    float av[8] = {a0.x, a0.y, a0.z, a0.w, a1.x, a1.y, a1.z, a1.w};
    short hi8[8], lo8[8];
    #pragma unroll
    for (int e = 0; e < 8; ++e) {
      sq = fmaf(av[e], av[e], sq);
      split1(av[e], hi8[e], lo8[e]);
    }
    *(short8*)(SM + awoff) = *(short8*)hi8;
    *(short8*)(SM + 4096 + awoff) = *(short8*)lo8;
    rA0 = *(const float4*)(hrow + 32);
    rA1 = *(const float4*)(hrow + 36);
  }
  RBAR();

#define KSTEP8(KB, CA0, CA1, NA0, NA1, UBH, UBL, PBH, PBL) do { \
    int buf_ = (KB) & 1; \
    const char* asb_ = SM + buf_ * 8192; \
    if ((KB) < 63) { \
      const char* bsrc_ = wfrag + (size_t)((KB) + 1) * 32768; \
      _Pragma("unroll") \
      for (int nf = 0; nf < 4; ++nf) { \
        PBH[nf] = *(const short8*)(bsrc_ + nf * 4096); \
        PBL[nf] = *(const short8*)(bsrc_ + nf * 4096 + 16384); \
      } \
    } \
    if ((KB) < 62) { \
      NA0 = *(const float4*)(hrow + ((KB) + 2) * 32); \
      NA1 = *(const float4*)(hrow + ((KB) + 2) * 32 + 4); \
    } \
    short8 ah_[4], al_[4]; \
    _Pragma("unroll") \
    for (int mf = 0; mf < 4; ++mf) { \
      ah_[mf] = *(const short8*)(asb_ + mf * 1024 + aroff); \
      al_[mf] = *(const short8*)(asb_ + 4096 + mf * 1024 + aroff); \
    } \
    __builtin_amdgcn_s_barrier(); \
    asm volatile("s_waitcnt lgkmcnt(0)" ::: "memory"); \
    __builtin_amdgcn_s_setprio(1); \
    _Pragma("unroll") \
    for (int nf = 0; nf < 2; ++nf) \
      _Pragma("unroll") \
      for (int mf = 0; mf < 4; ++mf) \
        acc[mf][nf] = __builtin_amdgcn_mfma_f32_16x16x32_bf16(ah_[mf], UBH[nf], acc[mf][nf], 0, 0, 0); \
    _Pragma("unroll") \
    for (int nf = 0; nf < 2; ++nf) \
      _Pragma("unroll") \
      for (int mf = 0; mf < 4; ++mf) \
        acc[mf][nf] = __builtin_amdgcn_mfma_f32_16x16x32_bf16(ah_[mf], UBL[nf], acc[mf][nf], 0, 0, 0); \
    _Pragma("unroll") \
    for (int nf = 0; nf < 2; ++nf) \
      _Pragma("unroll") \
      for (int mf = 0; mf < 4; ++mf) \
        acc[mf][nf] = __builtin_amdgcn_mfma_f32_16x16x32_bf16(al_[mf], UBH[nf], acc[mf][nf], 0, 0, 0); \
    __builtin_amdgcn_s_setprio(0); \
    __builtin_amdgcn_s_barrier(); \
    if ((KB) < 63) { \
      char* asn_ = SM + (buf_ ^ 1) * 8192; \
      float av_[8] = {CA0.x, CA0.y, CA0.z, CA0.w, CA1.x, CA1.y, CA1.z, CA1.w}; \
      short hi8_[8], lo8_[8]; \
      _Pragma("unroll") \
      for (int e = 0; e < 8; ++e) { \
        sq = fmaf(av_[e], av_[e], sq); \
        split1(av_[e], hi8_[e], lo8_[e]); \
      } \
      *(short8*)(asn_ + awoff) = *(short8*)hi8_; \
      *(short8*)(asn_ + 4096 + awoff) = *(short8*)lo8_; \
    } \
    __builtin_amdgcn_s_setprio(1); \
    _Pragma("unroll") \
    for (int nf = 2; nf < 4; ++nf) \
      _Pragma("unroll") \
      for (int mf = 0; mf < 4; ++mf) \
        acc[mf][nf] = __builtin_amdgcn_mfma_f32_16x16x32_bf16(ah_[mf], UBH[nf], acc[mf][nf], 0, 0, 0); \
    _Pragma("unroll") \
    for (int nf = 2; nf < 4; ++nf) \
      _Pragma("unroll") \
      for (int mf = 0; mf < 4; ++mf) \
        acc[mf][nf] = __builtin_amdgcn_mfma_f32_16x16x32_bf16(ah_[mf], UBL[nf], acc[mf][nf], 0, 0, 0); \
    _Pragma("unroll") \
    for (int nf = 2; nf < 4; ++nf) \
      _Pragma("unroll") \
      for (int mf = 0; mf < 4; ++mf) \
        acc[mf][nf] = __builtin_amdgcn_mfma_f32_16x16x32_bf16(al_[mf], UBH[nf], acc[mf][nf], 0, 0, 0); \
    __builtin_amdgcn_s_setprio(0); \
    asm volatile("s_waitcnt lgkmcnt(0)" ::: "memory"); \
    __builtin_amdgcn_s_barrier(); \
  } while (0)

  for (int kb2 = 0; kb2 < 32; ++kb2) {
    KSTEP8(2 * kb2,     rA0, rA1, rB0, rB1, B0h, B0l, B1h, B1l);
    KSTEP8(2 * kb2 + 1, rB0, rB1, rA0, rA1, B1h, B1l, B0h, B0l);
  }
#undef KSTEP8

  // ---- epilogue ----
  sq += __shfl_xor(sq, 1);
  sq += __shfl_xor(sq, 2);
  float* smf = (float*)SM;
  __syncthreads();
  if ((t & 3) == 0) smf[arow] = sq;
  __syncthreads();
  float irv[16];
  #pragma unroll
  for (int mf = 0; mf < 4; ++mf)
    #pragma unroll
    for (int r = 0; r < 4; ++r)
      irv[mf * 4 + r] = rsqrtf(smf[mf * 16 + kg * 4 + r] / (float)DIM + 1e-6f);
  __syncthreads();

  float* Kraw = smf;   // [64][256] with column XOR swizzle (row&7)<<2
  int j = w * 16 + fr;
  float bias0 = k_b[l * NKV + j];
  float bias1 = k_b[l * NKV + j + 64];
  float bias2 = k_b[l * NKV + j + 128];
  float bias3 = k_b[l * NKV + j + 192];
  #pragma unroll
  for (int mf = 0; mf < 4; ++mf) {
    #pragma unroll
    for (int r = 0; r < 4; ++r) {
      int row = mf * 16 + kg * 4 + r;
      int s = s0 + row;
      float ir = irv[mf * 4 + r];
      float v0 = acc[mf][0][r] * ir + bias0;
      float v1 = acc[mf][1][r] * ir + bias1;
      float v2 = acc[mf][2][r] * ir + bias2;
      float v3 = acc[mf][3][r] * ir + bias3;
      float cj = cost[s * HD + j], sj = sint[s * HD + j];
      float cj2 = cost[s * HD + j + 64], sj2 = sint[s * HD + j + 64];
      int sw = (row & 7) << 2;
      float* kr = Kraw + row * 256;
      kr[j ^ sw]           = v0 * cj - v1 * sj;
      kr[(j + 64) ^ sw]    = v1 * cj2 + v0 * sj2;
      kr[(j + 128) ^ sw]   = v2 * cj - v3 * sj;
      kr[(j + 192) ^ sw]   = v3 * cj2 + v2 * sj2;
    }
  }
  __syncthreads();

  int kc = sb >> 1, fb = (sb & 1) * 4;
  #pragma unroll
  for (int i = 0; i < 8; ++i) {
    int c = t + i * 256;
    int lc = c & 63, fl = (c >> 6) & 3, ts2 = (c >> 8) & 3, kv = c >> 10;
    int key = fl * 16 + (lc & 15);
    int d0 = kv * 128 + ts2 * 32 + (lc >> 4) * 8;
    int sw = (key & 7) << 2;
    float4 x0 = *(const float4*)(Kraw + key * 256 + (d0 ^ sw));
    float4 x1 = *(const float4*)(Kraw + key * 256 + ((d0 + 4) ^ sw));
    float av[8] = {x0.x, x0.y, x0.z, x0.w, x1.x, x1.y, x1.z, x1.w};
    short hi8[8], lo8[8];
    #pragma unroll
    for (int e = 0; e < 8; ++e) split1(av[e], hi8[e], lo8[e]);
    short* bb = Kblob + (size_t)((l * 2 + kv) * 32 + kc) * 32768
              + (size_t)((ts2 * 2 + 0) * 8 + fb + fl) * 512 + lc * 8;
    *(short8*)bb = *(short8*)hi8;
    *(short8*)(bb + 4096) = *(short8*)lo8;
  }
}

// ---------------- qgemm: Q = xq . q_w via bf16x3 MFMA; ks=8, nc=128, 2 blocks/CU ----------------
__global__ __launch_bounds__(256) void qgemm_kernel(
    const float* __restrict__ q_w, const short* __restrict__ Ablob,
    float* __restrict__ part) {
  __shared__ __align__(1024) char SM[65536];  // A 32KB | B dbuf 2x16KB
  int t = threadIdx.x;
  int nc = blockIdx.x, ks = blockIdx.y, l = blockIdx.z;
  int lane = t & 63, w = t >> 6;
  int fr = lane & 15, kg = lane >> 4;
  const char* abase = (const char*)(Ablob + (size_t)l * 131072 + (size_t)ks * 16384);
  const float* qwl = q_w + (size_t)l * DIM * NQE;

  #pragma unroll
  for (int c = 0; c < 8; ++c) {
    int chunk = w * 8 + c;
    GLOAD16(abase + chunk * 1024 + lane * 16, SM + chunk * 1024);
  }
  #pragma unroll
  for (int c = 0; c < 4; ++c) {
    int r2 = (w * 4 + c) * 2;
    const char* src = (const char*)(qwl + (size_t)(ks * 256 + r2 + (lane >> 5)) * NQE + nc * 128) + (lane & 31) * 16;
    GLOAD16(src, SM + 32768 + (w * 4 + c) * 1024);
  }
  f32x4 acc[2][2];
  #pragma unroll
  for (int mf = 0; mf < 2; ++mf)
    #pragma unroll
    for (int nf = 0; nf < 2; ++nf) acc[mf][nf] = (f32x4){0.f, 0.f, 0.f, 0.f};
  __syncthreads();

  for (int ts = 0; ts < 8; ++ts) {
    int buf = ts & 1;
    if (ts < 7) {
      #pragma unroll
      for (int c = 0; c < 4; ++c) {
        int r2 = (w * 4 + c) * 2;
        const char* src = (const char*)(qwl + (size_t)(ks * 256 + (ts + 1) * 32 + r2 + (lane >> 5)) * NQE + nc * 128) + (lane & 31) * 16;
        GLOAD16(src, SM + 32768 + (buf ^ 1) * 16384 + (w * 4 + c) * 1024);
      }
    }
    short8 ah[2], al[2];
    #pragma unroll
    for (int mf = 0; mf < 2; ++mf) {
      ah[mf] = *(const short8*)(SM + ts * 4096 + mf * 1024 + lane * 16);
      al[mf] = *(const short8*)(SM + ts * 4096 + 2048 + mf * 1024 + lane * 16);
    }
    const float* bt = (const float*)(SM + 32768 + buf * 16384);
    short8 bh[2], bl[2];
    #pragma unroll
    for (int nf = 0; nf < 2; ++nf) {
      int c = w * 32 + nf * 16 + fr;
      short bh8[8], bl8[8];
      #pragma unroll
      for (int e = 0; e < 8; ++e) {
        float v = bt[(kg * 8 + e) * 128 + c];
        split1(v, bh8[e], bl8[e]);
      }
      bh[nf] = *(short8*)bh8;
      bl[nf] = *(short8*)bl8;
    }
    #pragma unroll
    for (int nf = 0; nf < 2; ++nf)
      #pragma unroll
      for (int mf = 0; mf < 2; ++mf)
        acc[mf][nf] = __builtin_amdgcn_mfma_f32_16x16x32_bf16(ah[mf], bh[nf], acc[mf][nf], 0, 0, 0);
    #pragma unroll
    for (int nf = 0; nf < 2; ++nf)
      #pragma unroll
      for (int mf = 0; mf < 2; ++mf)
        acc[mf][nf] = __builtin_amdgcn_mfma_f32_16x16x32_bf16(ah[mf], bl[nf], acc[mf][nf], 0, 0, 0);
    #pragma unroll
    for (int nf = 0; nf < 2; ++nf)
      #pragma unroll
      for (int mf = 0; mf < 2; ++mf)
        acc[mf][nf] = __builtin_amdgcn_mfma_f32_16x16x32_bf16(al[mf], bh[nf], acc[mf][nf], 0, 0, 0);
    __syncthreads();
  }

  #pragma unroll
  for (int mf = 0; mf < 2; ++mf) {
    #pragma unroll
    for (int r = 0; r < 4; ++r) {
      int row = mf * 16 + kg * 4 + r;
      float* prow = part + ((size_t)((ks * LYR + l) * NQ + row)) * NQE + nc * 128;
      #pragma unroll
      for (int nf = 0; nf < 2; ++nf) {
        int col = w * 32 + nf * 16 + fr;
        prow[col] = acc[mf][nf][r];
      }
    }
  }
}

// ---------------- qredrope: sum 8 k-split partials + bias + rope + scale -> Qrope ----------------
__global__ __launch_bounds__(256) void qredrope_kernel(
    const float* __restrict__ part, const float* __restrict__ q_b,
    const float* __restrict__ cost, const float* __restrict__ sint,
    const int* __restrict__ q_idx, float* __restrict__ Qrope) {
  int p = blockIdx.x * 256 + threadIdx.x;  // L*NH*NQ*64 = 262144
  int j = p & 63, q = (p >> 6) & 31, h = (p >> 11) & 15, l = p >> 15;
  int n1 = h * HD + j, n2 = n1 + 64;
  float v1 = q_b[l * NQE + n1];
  float v2 = q_b[l * NQE + n2];
  #pragma unroll
  for (int ks = 0; ks < 8; ++ks) {
    const float* pr = part + ((size_t)((ks * LYR + l) * NQ + q)) * NQE;
    v1 += pr[n1];
    v2 += pr[n2];
  }
  int s = q_idx[q];
  float c1 = cost[s * HD + j],      s1 = sint[s * HD + j];
  float c2 = cost[s * HD + j + 64], s2 = sint[s * HD + j + 64];
  const float SC = 0.088388347648318447f;  // 1/sqrt(128)
  float* orow = Qrope + ((size_t)(l * NH + h) * NQ + q) * HD;
  orow[j]      = (v1 * c1 - v2 * s1) * SC;
  orow[j + 64] = (v2 * c2 + v1 * s2) * SC;
}

// ---------------- attn: fused scores + mask + softmax ----------------
// block = (l, h, 8 q-rows); S row kept in LDS fp32; K streamed global->reg from Kblob;
// XCD-bijective decode keeps each XCD's K-set L2-resident. One wave per row softmax.
__global__ __launch_bounds__(512) void attn_kernel(
    const float* __restrict__ Qrope, const short* __restrict__ Kblob,
    const int* __restrict__ q_idx, float* __restrict__ out) {
  __shared__ float smS[8 * 4104];   // 131328 B, row stride 4104 (bank-skewed)
  __shared__ int qiv8[8];
  int t = threadIdx.x;
  int bid = blockIdx.x;
  int xcd = bid & 7, idx = bid >> 3;
  int pp = 2 * xcd + (idx >> 5);
  int l = pp >> 1, kv = pp & 1;
  int hh = (idx >> 2) & 7, qg = idx & 3;
  int h = kv * 8 + hh;
  int q0 = qg * 8;
  int lane = t & 63, w = t >> 6;
  int g = lane >> 4;

  if (t < 8) qiv8[t] = q_idx[q0 + t];

  // A fragments from Qrope (rows 0..7 real, 8..15 zero)
  short8 Ah[4], Al[4];
  {
    int arow = lane & 15, akg = lane >> 4;
    if (arow < 8) {
      const float* qr = Qrope + ((size_t)(l * NH + h) * NQ + q0 + arow) * HD + akg * 8;
      #pragma unroll
      for (int ts = 0; ts < 4; ++ts) {
        float4 a0 = *(const float4*)(qr + ts * 32);
        float4 a1 = *(const float4*)(qr + ts * 32 + 4);
        float av[8] = {a0.x, a0.y, a0.z, a0.w, a1.x, a1.y, a1.z, a1.w};
        short hi8[8], lo8[8];
        #pragma unroll
        for (int e = 0; e < 8; ++e) split1(av[e], hi8[e], lo8[e]);
        Ah[ts] = *(short8*)hi8;
        Al[ts] = *(short8*)lo8;
      }
    } else {
      short z8[8] = {0, 0, 0, 0, 0, 0, 0, 0};
      #pragma unroll
      for (int ts = 0; ts < 4; ++ts) { Ah[ts] = *(short8*)z8; Al[ts] = *(short8*)z8; }
    }
  }
  const short* kbase = Kblob + (size_t)((l * 2 + kv) * 32) * 32768 + w * 512 + lane * 8;
  short8 K0h[4], K0l[4], K1h[4], K1l[4];
  #pragma unroll
  for (int ts = 0; ts < 4; ++ts) {
    K0h[ts] = *(const short8*)(kbase + ts * 8192);
    K0l[ts] = *(const short8*)(kbase + ts * 8192 + 4096);
  }
  __syncthreads();   // qiv8 visible

#define ACHUNK(KC, CH, CL, NH_, NL_) do { \
    if ((KC) < 31) { \
      const short* nb = kbase + (size_t)((KC) + 1) * 32768; \
      _Pragma("unroll") \
      for (int ts = 0; ts < 4; ++ts) { \
        NH_[ts] = *(const short8*)(nb + ts * 8192); \
        NL_[ts] = *(const short8*)(nb + ts * 8192 + 4096); \
      } \
    } \
    f32x4 acc = (f32x4){0.f, 0.f, 0.f, 0.f}; \
    _Pragma("unroll") \
    for (int ts = 0; ts < 4; ++ts) \
      acc = __builtin_amdgcn_mfma_f32_16x16x32_bf16(Ah[ts], CH[ts], acc, 0, 0, 0); \
    _Pragma("unroll") \
    for (int ts = 0; ts < 4; ++ts) \
      acc = __builtin_amdgcn_mfma_f32_16x16x32_bf16(Ah[ts], CL[ts], acc, 0, 0, 0); \
    _Pragma("unroll") \
    for (int ts = 0; ts < 4; ++ts) \
      acc = __builtin_amdgcn_mfma_f32_16x16x32_bf16(Al[ts], CH[ts], acc, 0, 0, 0); \
    if (g < 2) { \
      int key = (KC) * 128 + w * 16 + (lane & 15); \
      _Pragma("unroll") \
      for (int rr = 0; rr < 4; ++rr) { \
        int r8 = g * 4 + rr; \
        float v = (key > qiv8[r8]) ? -1e9f : acc[rr]; \
        smS[r8 * 4104 + key] = v; \
      } \
    } \
  } while (0)

  for (int kc2 = 0; kc2 < 16; ++kc2) {
    ACHUNK(2 * kc2,     K0h, K0l, K1h, K1l);
    ACHUNK(2 * kc2 + 1, K1h, K1l, K0h, K0l);
  }
#undef ACHUNK

  __syncthreads();
  // softmax: one wave per row
  int srow = w;
  float* S = smS + srow * 4104;
  float mx = -1e30f;
  #pragma unroll
  for (int c = 0; c < 16; ++c) {
    float4 x = *(const float4*)(S + c * 256 + lane * 4);
    mx = fmaxf(mx, fmaxf(fmaxf(x.x, x.y), fmaxf(x.z, x.w)));
  }
  #pragma unroll
  for (int off = 32; off >= 1; off >>= 1) mx = fmaxf(mx, __shfl_xor(mx, off));
  float sum = 0.f;
  #pragma unroll
  for (int c = 0; c < 16; ++c) {
    float4 x = *(const float4*)(S + c * 256 + lane * 4);
    x.x = __expf(x.x - mx); x.y = __expf(x.y - mx);
    x.z = __expf(x.z - mx); x.w = __expf(x.w - mx);
    sum += x.x + x.y + x.z + x.w;
    *(float4*)(S + c * 256 + lane * 4) = x;
  }
  #pragma unroll
  for (int off = 32; off >= 1; off >>= 1) sum += __shfl_xor(sum, off);
  float inv = 1.f / sum;
  float* orow = out + ((size_t)(l * NH + h) * NQ + q0 + srow) * SEQ;
  #pragma unroll
  for (int c = 0; c < 16; ++c) {
    float4 x = *(const float4*)(S + c * 256 + lane * 4);
    x.x *= inv; x.y *= inv; x.z *= inv; x.w *= inv;
    *(float4*)(orow + c * 256 + lane * 4) = x;
  }
}

extern "C" void kernel_launch(void* const* d_in, const int* in_sizes, int n_in,
                              void* d_out, int out_size, void* d_ws, size_t ws_size,
                              hipStream_t stream) {
  const float* hs   = (const float*)d_in[0];
  const float* ln_w = (const float*)d_in[1];
  const float* q_w  = (const float*)d_in[2];
  const float* q_b  = (const float*)d_in[3];
  const float* k_w  = (const float*)d_in[4];
  const float* k_b  = (const float*)d_in[5];
  const int* pos    = (const int*)d_in[6];
  const int* qidx   = (const int*)d_in[7];
  float* out = (float*)d_out;
  float* ws = (float*)d_ws;
  short* Ablob = (short*)(ws + WS_ABLOB);
  float* cost  = ws + WS_COS;
  float* sint  = ws + WS_SIN;
  float* part  = ws + WS_PART;
  short* W2    = (short*)(ws + WS_W2);
  short* Kblob = (short*)(ws + WS_KBLOB);
  float* Qrope = ws + WS_QROPE;

  prep_kernel<<<dim3(64, LYR), 256, 0, stream>>>(ln_w, k_w, W2);
  cossin_kernel<<<(SEQ * HD) / 256, 256, 0, stream>>>(pos, cost, sint);
  xqt_kernel<<<LYR, 256, 0, stream>>>(hs, ln_w, qidx, Ablob);
  kgemm_kernel<<<512, 256, 0, stream>>>(hs, W2, k_b, cost, sint, Kblob);
  qgemm_kernel<<<dim3(16, 8, LYR), 256, 0, stream>>>(q_w, Ablob, part);
  qredrope_kernel<<<1024, 256, 0, stream>>>(part, q_b, cost, sint, qidx, Qrope);
  attn_kernel<<<512, 512, 0, stream>>>(Qrope, Kblob, qidx, out);
}

// Round 17
// 258.168 us; speedup vs baseline: 1.0595x; 1.0100x over previous
//
#include <hip/hip_runtime.h>
#include <hip/hip_bf16.h>
#include <math.h>

#define LYR 8
#define SEQ 4096
#define DIM 2048
#define NH 16
#define HD 128
#define NQ 32
#define NKV 256   // KVH*HD
#define NQE 2048  // H*HD

typedef __attribute__((ext_vector_type(8))) short short8;
typedef __attribute__((ext_vector_type(4))) float f32x4;

// workspace layout (float units)
#define WS_ABLOB 256                       // 524288
#define WS_COS   524544                    // 524288
#define WS_SIN   1048832                   // 524288
#define WS_PART  2097408                   // 4194304 (16MB, ks=8 partials)
#define WS_W2    6291712                   // 4194304 floats = 8388608 shorts
#define WS_KBLOB 10486016                  // 8388608 floats = 16777216 shorts
// end 18874624 floats ~ 75.5 MB

__device__ __forceinline__ short f2bf(float x) {
  __hip_bfloat16 h = __float2bfloat16(x);
  return *(short*)&h;
}
__device__ __forceinline__ float bf2f(short s) {
  unsigned u = ((unsigned)(unsigned short)s) << 16;
  return __uint_as_float(u);
}

// cheap exact split: hi = truncate-to-bf16 (exact residual), lo = rne bf16 of residual
__device__ __forceinline__ void split1(float x, short& h, short& l) {
  unsigned b = __float_as_uint(x);
  h = (short)(b >> 16);
  float lo = x - __uint_as_float(b & 0xffff0000u);
  l = (short)((__float_as_uint(lo) + 0x8000u) >> 16);
}

#define GLOAD16(srcp, dstp) \
  __builtin_amdgcn_global_load_lds( \
      (const __attribute__((address_space(1))) unsigned int*)(srcp), \
      (__attribute__((address_space(3))) unsigned int*)(dstp), 16, 0, 0)

// raw barrier: drain LDS ops only; leave global loads in flight across the barrier
#define RBAR() asm volatile("s_waitcnt lgkmcnt(0)\n\ts_barrier" ::: "memory")

// ---------------- pre: fused prep (W2 blob) + cossin tables + xqt (A-frag blob) ----------------
// bid [0,512): prep; [512,2560): cossin; [2560,2568): xqt
__global__ __launch_bounds__(256) void pre_kernel(
    const float* __restrict__ ln_w, const float* __restrict__ k_w,
    const float* __restrict__ hs, const int* __restrict__ pos_ids,
    const int* __restrict__ q_idx, short* __restrict__ W2,
    float* __restrict__ cost, float* __restrict__ sint,
    short* __restrict__ Ablob) {
  int bid = blockIdx.x, t = threadIdx.x;
  if (bid < 512) {
    // ---- prep: W' = ln_w*k_w -> frag-lane-linear bf16 hi/lo blob ----
    int kb = bid & 63, l = bid >> 6;
    const float* kwl = k_w + (size_t)l * DIM * NKV;
    const float* lnl = ln_w + l * DIM;
    short* blob = W2 + (size_t)(l * 64 + kb) * 16384;
    #pragma unroll
    for (int i = 0; i < 4; ++i) {
      int p = t + i * 256;
      int fi = p >> 6, lane = p & 63;
      int n = fi * 16 + (lane & 15);
      int k0 = kb * 32 + (lane >> 4) * 8;
      short hi8[8], lo8[8];
      #pragma unroll
      for (int e = 0; e < 8; ++e) {
        float v = lnl[k0 + e] * kwl[(size_t)(k0 + e) * NKV + n];
        split1(v, hi8[e], lo8[e]);
      }
      *(short8*)(blob + p * 8) = *(short8*)hi8;
      *(short8*)(blob + 8192 + p * 8) = *(short8*)lo8;
    }
  } else if (bid < 2560) {
    // ---- cossin: mrope tables [S][HD] ----
    int idx = (bid - 512) * 256 + t;
    int s = idx >> 7, d = idx & 127;
    int tc = (d < 32) ? 0 : (d < 80 ? 1 : 2);
    int j = d & 63;
    double invf = pow(1000000.0, -(double)j / 64.0);
    double ph = (double)pos_ids[tc * SEQ + s] * invf;
    cost[idx] = (float)cos(ph);
    sint[idx] = (float)sin(ph);
  } else {
    // ---- xqt: fused inv_rms + A-frag blob ----
    __shared__ int qix[32];
    __shared__ float qir[32];
    int l = bid - 2560;
    if (t < 32) qix[t] = q_idx[t];
    __syncthreads();
    {
      int row = t >> 3, seg = t & 7;
      const float* src = hs + ((size_t)l * SEQ + qix[row]) * DIM + seg * 256;
      float sq = 0.f;
      #pragma unroll
      for (int i = 0; i < 64; ++i) {
        float4 v = *(const float4*)(src + i * 4);
        sq = fmaf(v.x, v.x, fmaf(v.y, v.y, fmaf(v.z, v.z, fmaf(v.w, v.w, sq))));
      }
      sq += __shfl_xor(sq, 1);
      sq += __shfl_xor(sq, 2);
      sq += __shfl_xor(sq, 4);
      if (seg == 0) qir[row] = rsqrtf(sq / (float)DIM + 1e-6f);
    }
    __syncthreads();
    int lane = t & 63, g4 = t >> 6;
    short* base = Ablob + (size_t)l * 131072;
    int row = lane & 15, kgl = lane >> 4;
    for (int i = 0; i < 64; ++i) {
      int group = g4 * 64 + i;                 // (kb, half, mf)
      int kb = group >> 2, half = (group >> 1) & 1, mf = group & 1;
      int r = row + mf * 16;
      int k0 = kb * 32 + kgl * 8;
      const float* src = hs + ((size_t)l * SEQ + qix[r]) * DIM + k0;
      const float* lnp = ln_w + l * DIM + k0;
      float ir = qir[r];
      float4 v0 = *(const float4*)src;
      float4 v1 = *(const float4*)(src + 4);
      float4 w0 = *(const float4*)lnp;
      float4 w1 = *(const float4*)(lnp + 4);
      float av[8] = {v0.x*w0.x, v0.y*w0.y, v0.z*w0.z, v0.w*w0.w,
                     v1.x*w1.x, v1.y*w1.y, v1.z*w1.z, v1.w*w1.w};
      short o8[8];
      #pragma unroll
      for (int e = 0; e < 8; ++e) {
        float v = av[e] * ir;
        short hh, ll;
        split1(v, hh, ll);
        o8[e] = half ? ll : hh;
      }
      *(short8*)(base + group * 512 + lane * 8) = *(short8*)o8;
    }
  }
}

// ---------------- kgemm: K proj bf16x3 MFMA, 2-phase-per-step CONVOY schedule ----------------
__global__ __launch_bounds__(256) void kgemm_kernel(
    const float* __restrict__ hs, const short* __restrict__ W2,
    const float* __restrict__ k_b, const float* __restrict__ cost,
    const float* __restrict__ sint, short* __restrict__ Kblob) {
  __shared__ __align__(1024) char SM[65536];

  int t = threadIdx.x;
  int fid = blockIdx.x;
  int l = fid & 7, sb = fid >> 3;
  int s0 = sb * 64;
  int lane = t & 63, w = t >> 6;
  int fr = lane & 15, kg = lane >> 4;
  int arow = t >> 2, akg = t & 3;

  const float* hrow = hs + ((size_t)l * SEQ + s0 + arow) * DIM + akg * 8;
  const char* wbase = (const char*)(W2 + (size_t)l * 64 * 16384);
  const char* wfrag = wbase + w * 1024 + lane * 16;

  int awoff = (arow >> 4) * 1024 + (((akg * 16 + (arow & 15)) * 16) ^ (akg << 5));
  int aroff = (lane * 16) ^ ((lane >> 4) << 5);

  f32x4 acc[4][4];
  #pragma unroll
  for (int mf = 0; mf < 4; ++mf)
    #pragma unroll
    for (int nf = 0; nf < 4; ++nf) acc[mf][nf] = (f32x4){0.f, 0.f, 0.f, 0.f};
  float sq = 0.f;
  float4 rA0, rA1, rB0, rB1;
  short8 B0h[4], B0l[4], B1h[4], B1l[4];

  {
    #pragma unroll
    for (int nf = 0; nf < 4; ++nf) {
      B0h[nf] = *(const short8*)(wfrag + nf * 4096);
      B0l[nf] = *(const short8*)(wfrag + nf * 4096 + 16384);
    }
    float4 a0 = *(const float4*)(hrow);
    float4 a1 = *(const float4*)(hrow + 4);
    float av[8] = {a0.x, a0.y, a0.z, a0.w, a1.x, a1.y, a1.z, a1.w};
    short hi8[8], lo8[8];
    #pragma unroll
    for (int e = 0; e < 8; ++e) {
      sq = fmaf(av[e], av[e], sq);
      split1(av[e], hi8[e], lo8[e]);
    }
    *(short8*)(SM + awoff) = *(short8*)hi8;
    *(short8*)(SM + 4096 + awoff) = *(short8*)lo8;
    rA0 = *(const float4*)(hrow + 32);
    rA1 = *(const float4*)(hrow + 36);
  }
  RBAR();

#define KSTEP8(KB, CA0, CA1, NA0, NA1, UBH, UBL, PBH, PBL) do { \
    int buf_ = (KB) & 1; \
    const char* asb_ = SM + buf_ * 8192; \
    if ((KB) < 63) { \
      const char* bsrc_ = wfrag + (size_t)((KB) + 1) * 32768; \
      _Pragma("unroll") \
      for (int nf = 0; nf < 4; ++nf) { \
        PBH[nf] = *(const short8*)(bsrc_ + nf * 4096); \
        PBL[nf] = *(const short8*)(bsrc_ + nf * 4096 + 16384); \
      } \
    } \
    if ((KB) < 62) { \
      NA0 = *(const float4*)(hrow + ((KB) + 2) * 32); \
      NA1 = *(const float4*)(hrow + ((KB) + 2) * 32 + 4); \
    } \
    short8 ah_[4], al_[4]; \
    _Pragma("unroll") \
    for (int mf = 0; mf < 4; ++mf) { \
      ah_[mf] = *(const short8*)(asb_ + mf * 1024 + aroff); \
      al_[mf] = *(const short8*)(asb_ + 4096 + mf * 1024 + aroff); \
    } \
    __builtin_amdgcn_s_barrier(); \
    asm volatile("s_waitcnt lgkmcnt(0)" ::: "memory"); \
    __builtin_amdgcn_s_setprio(1); \
    _Pragma("unroll") \
    for (int nf = 0; nf < 2; ++nf) \
      _Pragma("unroll") \
      for (int mf = 0; mf < 4; ++mf) \
        acc[mf][nf] = __builtin_amdgcn_mfma_f32_16x16x32_bf16(ah_[mf], UBH[nf], acc[mf][nf], 0, 0, 0); \
    _Pragma("unroll") \
    for (int nf = 0; nf < 2; ++nf) \
      _Pragma("unroll") \
      for (int mf = 0; mf < 4; ++mf) \
        acc[mf][nf] = __builtin_amdgcn_mfma_f32_16x16x32_bf16(ah_[mf], UBL[nf], acc[mf][nf], 0, 0, 0); \
    _Pragma("unroll") \
    for (int nf = 0; nf < 2; ++nf) \
      _Pragma("unroll") \
      for (int mf = 0; mf < 4; ++mf) \
        acc[mf][nf] = __builtin_amdgcn_mfma_f32_16x16x32_bf16(al_[mf], UBH[nf], acc[mf][nf], 0, 0, 0); \
    __builtin_amdgcn_s_setprio(0); \
    __builtin_amdgcn_s_barrier(); \
    if ((KB) < 63) { \
      char* asn_ = SM + (buf_ ^ 1) * 8192; \
      float av_[8] = {CA0.x, CA0.y, CA0.z, CA0.w, CA1.x, CA1.y, CA1.z, CA1.w}; \
      short hi8_[8], lo8_[8]; \
      _Pragma("unroll") \
      for (int e = 0; e < 8; ++e) { \
        sq = fmaf(av_[e], av_[e], sq); \
        split1(av_[e], hi8_[e], lo8_[e]); \
      } \
      *(short8*)(asn_ + awoff) = *(short8*)hi8_; \
      *(short8*)(asn_ + 4096 + awoff) = *(short8*)lo8_; \
    } \
    __builtin_amdgcn_s_setprio(1); \
    _Pragma("unroll") \
    for (int nf = 2; nf < 4; ++nf) \
      _Pragma("unroll") \
      for (int mf = 0; mf < 4; ++mf) \
        acc[mf][nf] = __builtin_amdgcn_mfma_f32_16x16x32_bf16(ah_[mf], UBH[nf], acc[mf][nf], 0, 0, 0); \
    _Pragma("unroll") \
    for (int nf = 2; nf < 4; ++nf) \
      _Pragma("unroll") \
      for (int mf = 0; mf < 4; ++mf) \
        acc[mf][nf] = __builtin_amdgcn_mfma_f32_16x16x32_bf16(ah_[mf], UBL[nf], acc[mf][nf], 0, 0, 0); \
    _Pragma("unroll") \
    for (int nf = 2; nf < 4; ++nf) \
      _Pragma("unroll") \
      for (int mf = 0; mf < 4; ++mf) \
        acc[mf][nf] = __builtin_amdgcn_mfma_f32_16x16x32_bf16(al_[mf], UBH[nf], acc[mf][nf], 0, 0, 0); \
    __builtin_amdgcn_s_setprio(0); \
    asm volatile("s_waitcnt lgkmcnt(0)" ::: "memory"); \
    __builtin_amdgcn_s_barrier(); \
  } while (0)

  for (int kb2 = 0; kb2 < 32; ++kb2) {
    KSTEP8(2 * kb2,     rA0, rA1, rB0, rB1, B0h, B0l, B1h, B1l);
    KSTEP8(2 * kb2 + 1, rB0, rB1, rA0, rA1, B1h, B1l, B0h, B0l);
  }
#undef KSTEP8

  // ---- epilogue ----
  sq += __shfl_xor(sq, 1);
  sq += __shfl_xor(sq, 2);
  float* smf = (float*)SM;
  __syncthreads();
  if ((t & 3) == 0) smf[arow] = sq;
  __syncthreads();
  float irv[16];
  #pragma unroll
  for (int mf = 0; mf < 4; ++mf)
    #pragma unroll
    for (int r = 0; r < 4; ++r)
      irv[mf * 4 + r] = rsqrtf(smf[mf * 16 + kg * 4 + r] / (float)DIM + 1e-6f);
  __syncthreads();

  float* Kraw = smf;   // [64][256] with column XOR swizzle (row&7)<<2
  int j = w * 16 + fr;
  float bias0 = k_b[l * NKV + j];
  float bias1 = k_b[l * NKV + j + 64];
  float bias2 = k_b[l * NKV + j + 128];
  float bias3 = k_b[l * NKV + j + 192];
  #pragma unroll
  for (int mf = 0; mf < 4; ++mf) {
    #pragma unroll
    for (int r = 0; r < 4; ++r) {
      int row = mf * 16 + kg * 4 + r;
      int s = s0 + row;
      float ir = irv[mf * 4 + r];
      float v0 = acc[mf][0][r] * ir + bias0;
      float v1 = acc[mf][1][r] * ir + bias1;
      float v2 = acc[mf][2][r] * ir + bias2;
      float v3 = acc[mf][3][r] * ir + bias3;
      float cj = cost[s * HD + j], sj = sint[s * HD + j];
      float cj2 = cost[s * HD + j + 64], sj2 = sint[s * HD + j + 64];
      int sw = (row & 7) << 2;
      float* kr = Kraw + row * 256;
      kr[j ^ sw]           = v0 * cj - v1 * sj;
      kr[(j + 64) ^ sw]    = v1 * cj2 + v0 * sj2;
      kr[(j + 128) ^ sw]   = v2 * cj - v3 * sj;
      kr[(j + 192) ^ sw]   = v3 * cj2 + v2 * sj2;
    }
  }
  __syncthreads();

  int kc = sb >> 1, fb = (sb & 1) * 4;
  #pragma unroll
  for (int i = 0; i < 8; ++i) {
    int c = t + i * 256;
    int lc = c & 63, fl = (c >> 6) & 3, ts2 = (c >> 8) & 3, kv = c >> 10;
    int key = fl * 16 + (lc & 15);
    int d0 = kv * 128 + ts2 * 32 + (lc >> 4) * 8;
    int sw = (key & 7) << 2;
    float4 x0 = *(const float4*)(Kraw + key * 256 + (d0 ^ sw));
    float4 x1 = *(const float4*)(Kraw + key * 256 + ((d0 + 4) ^ sw));
    float av[8] = {x0.x, x0.y, x0.z, x0.w, x1.x, x1.y, x1.z, x1.w};
    short hi8[8], lo8[8];
    #pragma unroll
    for (int e = 0; e < 8; ++e) split1(av[e], hi8[e], lo8[e]);
    short* bb = Kblob + (size_t)((l * 2 + kv) * 32 + kc) * 32768
              + (size_t)((ts2 * 2 + 0) * 8 + fb + fl) * 512 + lc * 8;
    *(short8*)bb = *(short8*)hi8;
    *(short8*)(bb + 4096) = *(short8*)lo8;
  }
}

// ---------------- qgemm: Q = xq . q_w via bf16x3 MFMA; ks=8, nc=128, 2 blocks/CU ----------------
__global__ __launch_bounds__(256) void qgemm_kernel(
    const float* __restrict__ q_w, const short* __restrict__ Ablob,
    float* __restrict__ part) {
  __shared__ __align__(1024) char SM[65536];  // A 32KB | B dbuf 2x16KB
  int t = threadIdx.x;
  int nc = blockIdx.x, ks = blockIdx.y, l = blockIdx.z;
  int lane = t & 63, w = t >> 6;
  int fr = lane & 15, kg = lane >> 4;
  const char* abase = (const char*)(Ablob + (size_t)l * 131072 + (size_t)ks * 16384);
  const float* qwl = q_w + (size_t)l * DIM * NQE;

  #pragma unroll
  for (int c = 0; c < 8; ++c) {
    int chunk = w * 8 + c;
    GLOAD16(abase + chunk * 1024 + lane * 16, SM + chunk * 1024);
  }
  #pragma unroll
  for (int c = 0; c < 4; ++c) {
    int r2 = (w * 4 + c) * 2;
    const char* src = (const char*)(qwl + (size_t)(ks * 256 + r2 + (lane >> 5)) * NQE + nc * 128) + (lane & 31) * 16;
    GLOAD16(src, SM + 32768 + (w * 4 + c) * 1024);
  }
  f32x4 acc[2][2];
  #pragma unroll
  for (int mf = 0; mf < 2; ++mf)
    #pragma unroll
    for (int nf = 0; nf < 2; ++nf) acc[mf][nf] = (f32x4){0.f, 0.f, 0.f, 0.f};
  __syncthreads();

  for (int ts = 0; ts < 8; ++ts) {
    int buf = ts & 1;
    if (ts < 7) {
      #pragma unroll
      for (int c = 0; c < 4; ++c) {
        int r2 = (w * 4 + c) * 2;
        const char* src = (const char*)(qwl + (size_t)(ks * 256 + (ts + 1) * 32 + r2 + (lane >> 5)) * NQE + nc * 128) + (lane & 31) * 16;
        GLOAD16(src, SM + 32768 + (buf ^ 1) * 16384 + (w * 4 + c) * 1024);
      }
    }
    short8 ah[2], al[2];
    #pragma unroll
    for (int mf = 0; mf < 2; ++mf) {
      ah[mf] = *(const short8*)(SM + ts * 4096 + mf * 1024 + lane * 16);
      al[mf] = *(const short8*)(SM + ts * 4096 + 2048 + mf * 1024 + lane * 16);
    }
    const float* bt = (const float*)(SM + 32768 + buf * 16384);
    short8 bh[2], bl[2];
    #pragma unroll
    for (int nf = 0; nf < 2; ++nf) {
      int c = w * 32 + nf * 16 + fr;
      short bh8[8], bl8[8];
      #pragma unroll
      for (int e = 0; e < 8; ++e) {
        float v = bt[(kg * 8 + e) * 128 + c];
        split1(v, bh8[e], bl8[e]);
      }
      bh[nf] = *(short8*)bh8;
      bl[nf] = *(short8*)bl8;
    }
    #pragma unroll
    for (int nf = 0; nf < 2; ++nf)
      #pragma unroll
      for (int mf = 0; mf < 2; ++mf)
        acc[mf][nf] = __builtin_amdgcn_mfma_f32_16x16x32_bf16(ah[mf], bh[nf], acc[mf][nf], 0, 0, 0);
    #pragma unroll
    for (int nf = 0; nf < 2; ++nf)
      #pragma unroll
      for (int mf = 0; mf < 2; ++mf)
        acc[mf][nf] = __builtin_amdgcn_mfma_f32_16x16x32_bf16(ah[mf], bl[nf], acc[mf][nf], 0, 0, 0);
    #pragma unroll
    for (int nf = 0; nf < 2; ++nf)
      #pragma unroll
      for (int mf = 0; mf < 2; ++mf)
        acc[mf][nf] = __builtin_amdgcn_mfma_f32_16x16x32_bf16(al[mf], bh[nf], acc[mf][nf], 0, 0, 0);
    __syncthreads();
  }

  #pragma unroll
  for (int mf = 0; mf < 2; ++mf) {
    #pragma unroll
    for (int r = 0; r < 4; ++r) {
      int row = mf * 16 + kg * 4 + r;
      float* prow = part + ((size_t)((ks * LYR + l) * NQ + row)) * NQE + nc * 128;
      #pragma unroll
      for (int nf = 0; nf < 2; ++nf) {
        int col = w * 32 + nf * 16 + fr;
        prow[col] = acc[mf][nf][r];
      }
    }
  }
}

// ---------------- attn: fused Q-reduce+rope + scores + mask + softmax ----------------
// block = (l, h, 8 q-rows); prologue builds the block's 8x128 roped+scaled Q rows
// from the qgemm partials (part read exactly once chip-wide); S row in LDS fp32;
// K streamed global->reg from Kblob; XCD-bijective decode for L2 locality.
__global__ __launch_bounds__(512) void attn_kernel(
    const float* __restrict__ part, const float* __restrict__ q_b,
    const float* __restrict__ cost, const float* __restrict__ sint,
    const short* __restrict__ Kblob, const int* __restrict__ q_idx,
    float* __restrict__ out) {
  __shared__ float smS[8 * 4104];   // 131328 B, row stride 4104 (bank-skewed)
  __shared__ float smQ[8][128];     // roped+scaled Q rows (4 KB)
  __shared__ int qiv8[8];
  int t = threadIdx.x;
  int bid = blockIdx.x;
  int xcd = bid & 7, idx = bid >> 3;
  int pp = 2 * xcd + (idx >> 5);
  int l = pp >> 1, kv = pp & 1;
  int hh = (idx >> 2) & 7, qg = idx & 3;
  int h = kv * 8 + hh;
  int q0 = qg * 8;
  int lane = t & 63, w = t >> 6;
  int g = lane >> 4;

  if (t < 8) qiv8[t] = q_idx[q0 + t];

  // prologue: build this block's Q rows (sum 8 partials + bias, rope, scale)
  {
    int row = t >> 6, j = t & 63;       // 512 threads = 8 rows x 64 pairs
    int q = q0 + row;
    int n1 = h * HD + j;
    float v1 = q_b[l * NQE + n1];
    float v2 = q_b[l * NQE + n1 + 64];
    #pragma unroll
    for (int ks = 0; ks < 8; ++ks) {
      const float* pr = part + ((size_t)((ks * LYR + l) * NQ + q)) * NQE + n1;
      v1 += pr[0];
      v2 += pr[64];
    }
    int s = q_idx[q];
    float c1 = cost[s * HD + j],      s1 = sint[s * HD + j];
    float c2 = cost[s * HD + j + 64], s2 = sint[s * HD + j + 64];
    const float SC = 0.088388347648318447f;  // 1/sqrt(128)
    smQ[row][j]      = (v1 * c1 - v2 * s1) * SC;
    smQ[row][j + 64] = (v2 * c2 + v1 * s2) * SC;
  }
  __syncthreads();   // smQ + qiv8 visible

  // A fragments from smQ (rows 0..7 real, 8..15 zero)
  short8 Ah[4], Al[4];
  {
    int arow = lane & 15, akg = lane >> 4;
    if (arow < 8) {
      const float* qr = &smQ[arow][0] + akg * 8;
      #pragma unroll
      for (int ts = 0; ts < 4; ++ts) {
        float4 a0 = *(const float4*)(qr + ts * 32);
        float4 a1 = *(const float4*)(qr + ts * 32 + 4);
        float av[8] = {a0.x, a0.y, a0.z, a0.w, a1.x, a1.y, a1.z, a1.w};
        short hi8[8], lo8[8];
        #pragma unroll
        for (int e = 0; e < 8; ++e) split1(av[e], hi8[e], lo8[e]);
        Ah[ts] = *(short8*)hi8;
        Al[ts] = *(short8*)lo8;
      }
    } else {
      short z8[8] = {0, 0, 0, 0, 0, 0, 0, 0};
      #pragma unroll
      for (int ts = 0; ts < 4; ++ts) { Ah[ts] = *(short8*)z8; Al[ts] = *(short8*)z8; }
    }
  }
  const short* kbase = Kblob + (size_t)((l * 2 + kv) * 32) * 32768 + w * 512 + lane * 8;
  short8 K0h[4], K0l[4], K1h[4], K1l[4];
  #pragma unroll
  for (int ts = 0; ts < 4; ++ts) {
    K0h[ts] = *(const short8*)(kbase + ts * 8192);
    K0l[ts] = *(const short8*)(kbase + ts * 8192 + 4096);
  }

#define ACHUNK(KC, CH, CL, NH_, NL_) do { \
    if ((KC) < 31) { \
      const short* nb = kbase + (size_t)((KC) + 1) * 32768; \
      _Pragma("unroll") \
      for (int ts = 0; ts < 4; ++ts) { \
        NH_[ts] = *(const short8*)(nb + ts * 8192); \
        NL_[ts] = *(const short8*)(nb + ts * 8192 + 4096); \
      } \
    } \
    f32x4 acc = (f32x4){0.f, 0.f, 0.f, 0.f}; \
    _Pragma("unroll") \
    for (int ts = 0; ts < 4; ++ts) \
      acc = __builtin_amdgcn_mfma_f32_16x16x32_bf16(Ah[ts], CH[ts], acc, 0, 0, 0); \
    _Pragma("unroll") \
    for (int ts = 0; ts < 4; ++ts) \
      acc = __builtin_amdgcn_mfma_f32_16x16x32_bf16(Ah[ts], CL[ts], acc, 0, 0, 0); \
    _Pragma("unroll") \
    for (int ts = 0; ts < 4; ++ts) \
      acc = __builtin_amdgcn_mfma_f32_16x16x32_bf16(Al[ts], CH[ts], acc, 0, 0, 0); \
    if (g < 2) { \
      int key = (KC) * 128 + w * 16 + (lane & 15); \
      _Pragma("unroll") \
      for (int rr = 0; rr < 4; ++rr) { \
        int r8 = g * 4 + rr; \
        float v = (key > qiv8[r8]) ? -1e9f : acc[rr]; \
        smS[r8 * 4104 + key] = v; \
      } \
    } \
  } while (0)

  for (int kc2 = 0; kc2 < 16; ++kc2) {
    ACHUNK(2 * kc2,     K0h, K0l, K1h, K1l);
    ACHUNK(2 * kc2 + 1, K1h, K1l, K0h, K0l);
  }
#undef ACHUNK

  __syncthreads();
  // softmax: one wave per row
  int srow = w;
  float* S = smS + srow * 4104;
  float mx = -1e30f;
  #pragma unroll
  for (int c = 0; c < 16; ++c) {
    float4 x = *(const float4*)(S + c * 256 + lane * 4);
    mx = fmaxf(mx, fmaxf(fmaxf(x.x, x.y), fmaxf(x.z, x.w)));
  }
  #pragma unroll
  for (int off = 32; off >= 1; off >>= 1) mx = fmaxf(mx, __shfl_xor(mx, off));
  float sum = 0.f;
  #pragma unroll
  for (int c = 0; c < 16; ++c) {
    float4 x = *(const float4*)(S + c * 256 + lane * 4);
    x.x = __expf(x.x - mx); x.y = __expf(x.y - mx);
    x.z = __expf(x.z - mx); x.w = __expf(x.w - mx);
    sum += x.x + x.y + x.z + x.w;
    *(float4*)(S + c * 256 + lane * 4) = x;
  }
  #pragma unroll
  for (int off = 32; off >= 1; off >>= 1) sum += __shfl_xor(sum, off);
  float inv = 1.f / sum;
  float* orow = out + ((size_t)(l * NH + h) * NQ + q0 + srow) * SEQ;
  #pragma unroll
  for (int c = 0; c < 16; ++c) {
    float4 x = *(const float4*)(S + c * 256 + lane * 4);
    x.x *= inv; x.y *= inv; x.z *= inv; x.w *= inv;
    *(float4*)(orow + c * 256 + lane * 4) = x;
  }
}

extern "C" void kernel_launch(void* const* d_in, const int* in_sizes, int n_in,
                              void* d_out, int out_size, void* d_ws, size_t ws_size,
                              hipStream_t stream) {
  const float* hs   = (const float*)d_in[0];
  const float* ln_w = (const float*)d_in[1];
  const float* q_w  = (const float*)d_in[2];
  const float* q_b  = (const float*)d_in[3];
  const float* k_w  = (const float*)d_in[4];
  const float* k_b  = (const float*)d_in[5];
  const int* pos    = (const int*)d_in[6];
  const int* qidx   = (const int*)d_in[7];
  float* out = (float*)d_out;
  float* ws = (float*)d_ws;
  short* Ablob = (short*)(ws + WS_ABLOB);
  float* cost  = ws + WS_COS;
  float* sint  = ws + WS_SIN;
  float* part  = ws + WS_PART;
  short* W2    = (short*)(ws + WS_W2);
  short* Kblob = (short*)(ws + WS_KBLOB);

  pre_kernel<<<2568, 256, 0, stream>>>(ln_w, k_w, hs, pos, qidx, W2, cost, sint, Ablob);
  kgemm_kernel<<<512, 256, 0, stream>>>(hs, W2, k_b, cost, sint, Kblob);
  qgemm_kernel<<<dim3(16, 8, LYR), 256, 0, stream>>>(q_w, Ablob, part);
  attn_kernel<<<512, 512, 0, stream>>>(part, q_b, cost, sint, Kblob, qidx, out);
}